// Round 10
// baseline (238.247 us; speedup 1.0000x reference)
//
#include <hip/hip_runtime.h>

// Problem dims (fixed by reference)
#define C_DIM 2048
#define T_DIM 1024
#define R_DIM 32
#define K_DIM 128

#define NC 16                   // c-chunks (proven best; part traffic = NC*K*T)
#define KG 2                    // k's per thread (neutral vs 4; R7 config)
#define CCHUNK (C_DIM / NC)     // 128

// clang native vector type: __builtin_nontemporal_load requires a pointer to
// scalar or native vector (HIP_vector_type<float,4> is a class -> rejected).
typedef float f32x4 __attribute__((ext_vector_type(4)));

// Kernel A: uv[c][t] = sum_r U[c][t][r] * V[r][t]  — LDS-staged, XOR-swizzled.
// Each block owns 256 consecutive (c,t) pairs = 32 KiB of U, staged with 8
// contiguous float4 NONTEMPORAL loads per thread (U is a use-once 268 MB
// stream; keep it out of cache retention). LDS layout: float4 chunk q of pair
// p lives at slot p*8 + (q ^ (p&7)); both ds_write_b128 and ds_read_b128 run
// at the structural-minimum 8 cycles/wave.
__global__ void uv_kernel(const float* __restrict__ U, const float* __restrict__ V,
                          float* __restrict__ uv) {
    __shared__ f32x4 su[256 * 8];
    const int tid = threadIdx.x;
    const size_t p0 = (size_t)blockIdx.x * 256;      // first (c*T+t) pair of block

    const f32x4* ub = reinterpret_cast<const f32x4*>(U + p0 * R_DIM);
#pragma unroll
    for (int qq = 0; qq < 8; ++qq) {
        int j = qq * 256 + tid;                      // float4 index in block slice
        int p = j >> 3;                              // local pair
        int q = j & 7;                               // chunk within pair
        su[p * 8 + (q ^ (p & 7))] = __builtin_nontemporal_load(ub + j);
    }
    __syncthreads();

    const size_t pair = p0 + tid;                    // this thread's c*T + t
    const int t = (int)(pair & (T_DIM - 1));         // block t-span never wraps
    const float* vb = V + t;
    float acc = 0.f;
#pragma unroll
    for (int q = 0; q < 8; ++q) {
        f32x4 uq = su[tid * 8 + (q ^ (tid & 7))];    // chunk q: r = 4q..4q+3
        acc += uq.x * vb[(size_t)(4 * q + 0) * T_DIM];
        acc += uq.y * vb[(size_t)(4 * q + 1) * T_DIM];
        acc += uq.z * vb[(size_t)(4 * q + 2) * T_DIM];
        acc += uq.w * vb[(size_t)(4 * q + 3) * T_DIM];
    }
    uv[pair] = acc;
}

// Kernel B: partial[chunk][k][t] = sum_{c in chunk} uv[c][t] * X[k][c][t]
// X is a use-once 1 GiB stream: load it NONTEMPORAL so it doesn't evict the
// uv working set (re-read 64x, wants L2/LLC residency). uv/part keep normal
// cached loads/stores. All accesses float4 (1 KiB per wave-instr).
__global__ void partial_kernel(const float* __restrict__ X, const float* __restrict__ uv,
                               float* __restrict__ part) {
    int tid = blockIdx.x * blockDim.x + threadIdx.x;
    int t4    = tid & (T_DIM / 4 - 1);              // 0..255
    int kg    = (tid >> 8) & ((K_DIM / KG) - 1);    // 0..63
    int chunk = tid >> 14;                          // 0..NC-1 (14 = 8 + log2(K/KG))
    int t0 = t4 * 4;
    int k0 = kg * KG;
    int c0 = chunk * CCHUNK;

    const size_t kstride = (size_t)C_DIM * T_DIM;   // stride between k planes
    const f32x4* xb0 = reinterpret_cast<const f32x4*>(X + (size_t)k0 * kstride + (size_t)c0 * T_DIM + t0);
    const f32x4* xb1 = reinterpret_cast<const f32x4*>(X + (size_t)(k0 + 1) * kstride + (size_t)c0 * T_DIM + t0);
    const float* uvp = uv + (size_t)c0 * T_DIM + t0;

    float4 a0 = make_float4(0.f, 0.f, 0.f, 0.f);
    float4 a1 = a0;

#pragma unroll 4
    for (int c = 0; c < CCHUNK; ++c) {
        size_t off = (size_t)c * T_DIM;
        float4 w  = *reinterpret_cast<const float4*>(uvp + off);
        f32x4 x0 = __builtin_nontemporal_load(xb0 + (off >> 2));
        f32x4 x1 = __builtin_nontemporal_load(xb1 + (off >> 2));
        a0.x += w.x * x0.x; a0.y += w.y * x0.y; a0.z += w.z * x0.z; a0.w += w.w * x0.w;
        a1.x += w.x * x1.x; a1.y += w.y * x1.y; a1.z += w.z * x1.z; a1.w += w.w * x1.w;
    }
    float* p = part + ((size_t)chunk * K_DIM + k0) * T_DIM + t0;
    *reinterpret_cast<float4*>(p + 0 * T_DIM) = a0;
    *reinterpret_cast<float4*>(p + 1 * T_DIM) = a1;
}

// Kernel C: out[k][t] = sum_chunk partial[chunk][k][t], float4 over t
__global__ void reduce_kernel(const float* __restrict__ part, float* __restrict__ out) {
    int tid = blockIdx.x * blockDim.x + threadIdx.x;  // (k*T + t)/4
    size_t o = (size_t)tid * 4;
    float4 acc = make_float4(0.f, 0.f, 0.f, 0.f);
#pragma unroll
    for (int ch = 0; ch < NC; ++ch) {
        float4 v = *reinterpret_cast<const float4*>(part + (size_t)ch * K_DIM * T_DIM + o);
        acc.x += v.x; acc.y += v.y; acc.z += v.z; acc.w += v.w;
    }
    *reinterpret_cast<float4*>(out + o) = acc;
}

extern "C" void kernel_launch(void* const* d_in, const int* in_sizes, int n_in,
                              void* d_out, int out_size, void* d_ws, size_t ws_size,
                              hipStream_t stream) {
    // inputs: [0]=recording_index (unused), [1]=X (K,C,T), [2]=U (C,T,R), [3]=V (R,T)
    const float* X = (const float*)d_in[1];
    const float* U = (const float*)d_in[2];
    const float* V = (const float*)d_in[3];
    float* out = (float*)d_out;

    float* uv   = (float*)d_ws;                          // C*T floats = 8 MiB
    float* part = uv + (size_t)C_DIM * T_DIM;            // NC*K*T floats = 8 MiB

    uv_kernel<<<C_DIM * T_DIM / 256, 256, 0, stream>>>(U, V, uv);
    partial_kernel<<<NC * (K_DIM / KG) * (T_DIM / 4) / 256, 256, 0, stream>>>(X, uv, part);
    reduce_kernel<<<K_DIM * T_DIM / 4 / 256, 256, 0, stream>>>(part, out);
}

// Round 11
// 229.071 us; speedup vs baseline: 1.0401x; 1.0401x over previous
//
#include <hip/hip_runtime.h>

// Problem dims (fixed by reference)
#define C_DIM 2048
#define T_DIM 1024
#define R_DIM 32
#define K_DIM 128

#define NC 16                   // c-chunks (proven best; part traffic = NC*K*T)
#define KG 2                    // k's per thread (neutral vs 4; R7 config)
#define CCHUNK (C_DIM / NC)     // 128

// clang native vector type: __builtin_nontemporal_load requires a pointer to
// scalar or native vector (HIP_vector_type<float,4> is a class -> rejected).
typedef float f32x4 __attribute__((ext_vector_type(4)));

// Kernel A: uv[c][t] = sum_r U[c][t][r] * V[r][t]  — LDS-staged, XOR-swizzled.
// Each block owns 256 consecutive (c,t) pairs = 32 KiB of U, staged with 8
// contiguous float4 loads per thread (1 KiB per wave-instr). CACHED loads:
// R10 showed nontemporal U regresses +8.6us (no reuse-set to protect in A;
// NT forfeits L2 aggregation of the staging stream). LDS layout: float4
// chunk q of pair p at slot p*8 + (q ^ (p&7)); both ds_write_b128 and
// ds_read_b128 run at the structural-minimum 8 cycles/wave.
__global__ void uv_kernel(const float* __restrict__ U, const float* __restrict__ V,
                          float* __restrict__ uv) {
    __shared__ float4 su[256 * 8];
    const int tid = threadIdx.x;
    const size_t p0 = (size_t)blockIdx.x * 256;      // first (c*T+t) pair of block

    const float4* ub = reinterpret_cast<const float4*>(U + p0 * R_DIM);
#pragma unroll
    for (int qq = 0; qq < 8; ++qq) {
        int j = qq * 256 + tid;                      // float4 index in block slice
        int p = j >> 3;                              // local pair
        int q = j & 7;                               // chunk within pair
        su[p * 8 + (q ^ (p & 7))] = ub[j];
    }
    __syncthreads();

    const size_t pair = p0 + tid;                    // this thread's c*T + t
    const int t = (int)(pair & (T_DIM - 1));         // block t-span never wraps
    const float* vb = V + t;
    float acc = 0.f;
#pragma unroll
    for (int q = 0; q < 8; ++q) {
        float4 uq = su[tid * 8 + (q ^ (tid & 7))];   // chunk q: r = 4q..4q+3
        acc += uq.x * vb[(size_t)(4 * q + 0) * T_DIM];
        acc += uq.y * vb[(size_t)(4 * q + 1) * T_DIM];
        acc += uq.z * vb[(size_t)(4 * q + 2) * T_DIM];
        acc += uq.w * vb[(size_t)(4 * q + 3) * T_DIM];
    }
    uv[pair] = acc;
}

// Kernel B: partial[chunk][k][t] = sum_{c in chunk} uv[c][t] * X[k][c][t]
// X is a use-once 1 GiB stream: load it NONTEMPORAL so it doesn't evict the
// uv working set (re-read 64x, wants L2/LLC residency). uv/part keep normal
// cached loads/stores. All accesses float4 (1 KiB per wave-instr).
__global__ void partial_kernel(const float* __restrict__ X, const float* __restrict__ uv,
                               float* __restrict__ part) {
    int tid = blockIdx.x * blockDim.x + threadIdx.x;
    int t4    = tid & (T_DIM / 4 - 1);              // 0..255
    int kg    = (tid >> 8) & ((K_DIM / KG) - 1);    // 0..63
    int chunk = tid >> 14;                          // 0..NC-1 (14 = 8 + log2(K/KG))
    int t0 = t4 * 4;
    int k0 = kg * KG;
    int c0 = chunk * CCHUNK;

    const size_t kstride = (size_t)C_DIM * T_DIM;   // stride between k planes
    const f32x4* xb0 = reinterpret_cast<const f32x4*>(X + (size_t)k0 * kstride + (size_t)c0 * T_DIM + t0);
    const f32x4* xb1 = reinterpret_cast<const f32x4*>(X + (size_t)(k0 + 1) * kstride + (size_t)c0 * T_DIM + t0);
    const float* uvp = uv + (size_t)c0 * T_DIM + t0;

    float4 a0 = make_float4(0.f, 0.f, 0.f, 0.f);
    float4 a1 = a0;

#pragma unroll 4
    for (int c = 0; c < CCHUNK; ++c) {
        size_t off = (size_t)c * T_DIM;
        float4 w  = *reinterpret_cast<const float4*>(uvp + off);
        f32x4 x0 = __builtin_nontemporal_load(xb0 + (off >> 2));
        f32x4 x1 = __builtin_nontemporal_load(xb1 + (off >> 2));
        a0.x += w.x * x0.x; a0.y += w.y * x0.y; a0.z += w.z * x0.z; a0.w += w.w * x0.w;
        a1.x += w.x * x1.x; a1.y += w.y * x1.y; a1.z += w.z * x1.z; a1.w += w.w * x1.w;
    }
    float* p = part + ((size_t)chunk * K_DIM + k0) * T_DIM + t0;
    *reinterpret_cast<float4*>(p + 0 * T_DIM) = a0;
    *reinterpret_cast<float4*>(p + 1 * T_DIM) = a1;
}

// Kernel C: out[k][t] = sum_chunk partial[chunk][k][t], float4 over t
__global__ void reduce_kernel(const float* __restrict__ part, float* __restrict__ out) {
    int tid = blockIdx.x * blockDim.x + threadIdx.x;  // (k*T + t)/4
    size_t o = (size_t)tid * 4;
    float4 acc = make_float4(0.f, 0.f, 0.f, 0.f);
#pragma unroll
    for (int ch = 0; ch < NC; ++ch) {
        float4 v = *reinterpret_cast<const float4*>(part + (size_t)ch * K_DIM * T_DIM + o);
        acc.x += v.x; acc.y += v.y; acc.z += v.z; acc.w += v.w;
    }
    *reinterpret_cast<float4*>(out + o) = acc;
}

extern "C" void kernel_launch(void* const* d_in, const int* in_sizes, int n_in,
                              void* d_out, int out_size, void* d_ws, size_t ws_size,
                              hipStream_t stream) {
    // inputs: [0]=recording_index (unused), [1]=X (K,C,T), [2]=U (C,T,R), [3]=V (R,T)
    const float* X = (const float*)d_in[1];
    const float* U = (const float*)d_in[2];
    const float* V = (const float*)d_in[3];
    float* out = (float*)d_out;

    float* uv   = (float*)d_ws;                          // C*T floats = 8 MiB
    float* part = uv + (size_t)C_DIM * T_DIM;            // NC*K*T floats = 8 MiB

    uv_kernel<<<C_DIM * T_DIM / 256, 256, 0, stream>>>(U, V, uv);
    partial_kernel<<<NC * (K_DIM / KG) * (T_DIM / 4) / 256, 256, 0, stream>>>(X, uv, part);
    reduce_kernel<<<K_DIM * T_DIM / 4 / 256, 256, 0, stream>>>(part, out);
}